// Round 12
// baseline (160.003 us; speedup 1.0000x reference)
//
#include <hip/hip_runtime.h>
#include <hip/hip_bf16.h>

#define B_ 8
#define K_ 8
#define H_ 256
#define W_ 256
#define HW (H_*W_)

// ---------------------------------------------------------------------------
// helpers
// ---------------------------------------------------------------------------
__device__ __forceinline__ unsigned short f2bf(float f) {
    __hip_bfloat16 h = __float2bfloat16(f);  // RNE
    return *reinterpret_cast<unsigned short*>(&h);
}
// extract bf16 channel c (elem 2k low 16 bits, 2k+1 high) as f32; c is
// compile-time under #pragma unroll -> pure shift/mask, no unpack arrays.
__device__ __forceinline__ float bfex(uint4 u, int c) {
    const unsigned int w = (&u.x)[c >> 1];
    return __uint_as_float((c & 1) ? (w & 0xffff0000u) : (w << 16));
}
// sum within each 32-lane half of a wave; result valid in lanes 0 and 32
__device__ __forceinline__ float half_reduce(float v) {
    v += __shfl_down(v, 16, 64);
    v += __shfl_down(v, 8, 64);
    v += __shfl_down(v, 4, 64);
    v += __shfl_down(v, 2, 64);
    v += __shfl_down(v, 1, 64);
    return v;
}
// full 64-lane wave reduce; result valid in lane 0 (R5's proven tree)
__device__ __forceinline__ float wave_reduce(float v) {
    v += __shfl_down(v, 32, 64);
    v += __shfl_down(v, 16, 64);
    v += __shfl_down(v, 8, 64);
    v += __shfl_down(v, 4, 64);
    v += __shfl_down(v, 2, 64);
    v += __shfl_down(v, 1, 64);
    return v;
}
// fine-grained coherent (cache-bypassing) accesses — NO L2 fences anywhere
__device__ __forceinline__ void cstoref(float* p, float v) {
    __hip_atomic_store(p, v, __ATOMIC_RELAXED, __HIP_MEMORY_SCOPE_AGENT);
}
__device__ __forceinline__ float cloadf(const float* p) {
    return __hip_atomic_load((float*)p, __ATOMIC_RELAXED, __HIP_MEMORY_SCOPE_AGENT);
}
__device__ __forceinline__ void cstored(double* p, double v) {
    __hip_atomic_store(p, v, __ATOMIC_RELAXED, __HIP_MEMORY_SCOPE_AGENT);
}
__device__ __forceinline__ double cloadd(const double* p) {
    return __hip_atomic_load((double*)p, __ATOMIC_RELAXED, __HIP_MEMORY_SCOPE_AGENT);
}
__device__ __forceinline__ void cstoreu(unsigned int* p, unsigned int v) {
    __hip_atomic_store(p, v, __ATOMIC_RELAXED, __HIP_MEMORY_SCOPE_AGENT);
}
__device__ __forceinline__ unsigned int cloadu(const unsigned int* p) {
    return __hip_atomic_load((unsigned int*)p, __ATOMIC_RELAXED, __HIP_MEMORY_SCOPE_AGENT);
}
// bounded single-flag poll (leader thread) — fast-fail, never hangs
__device__ __forceinline__ void wait_count(unsigned int* p, unsigned int target) {
    for (int i = 0; i < 20000; ++i) {
        if (cloadu(p) >= target) return;
        __builtin_amdgcn_s_sleep(1);
    }
}
// wave-parallel 64-flag wait: lanes 0..63 each poll ONE flag (own cacheline,
// stride 16 u32 = 64 B). Writers store flags in parallel (no RMW chain).
// Bounded; all lanes exit together via uniform __ballot. Proven R11.
__device__ __forceinline__ void wait_flags64(unsigned int* base, int lane) {
    for (int i = 0; i < 20000; ++i) {
        const unsigned int v = cloadu(base + lane * 16);
        if (!__ballot(v == 0u)) return;
        __builtin_amdgcn_s_sleep(1);
    }
}

// per-pixel warp + bilinear + residual; TG fragment in registers (bfex form)
__device__ __forceinline__ void pixel_accum(
    const uint4* __restrict__ imgT,
    const uint4 t0, const uint4 g0, const uint4 g1,
    int b, int x, int y,
    float h00, float h01, float h02, float h10, float h11, float h12,
    float h20, float h21, float* aa) {
    const float X = (float)x - 127.5f, Y = (float)y - 127.5f;
    const float zw = h20 * X + h21 * Y + 1.f;
    const float Xw = (h00 * X + h01 * Y + h02) / zw + 127.5f;
    const float Yw = (h10 * X + h11 * Y + h12) / zw + 127.5f;
    const float NLO = -1.f + 2.f / 256.f, NHI = 1.f - 2.f / 256.f;
    const float xn = Xw / 127.5f - 1.f, yn = Yw / 127.5f - 1.f;
    const float m = (xn > NLO && xn < NHI && yn > NLO && yn < NHI) ? 1.f : 0.f;

    const float x0f = floorf(Xw), y0f = floorf(Yw);
    const float fx = Xw - x0f, fy = Yw - y0f;
    const float x1f = x0f + 1.f, y1f = y0f + 1.f;
    const bool vx0 = (x0f >= 0.f) && (x0f <= 255.f);
    const bool vx1 = (x1f >= 0.f) && (x1f <= 255.f);
    const bool vy0 = (y0f >= 0.f) && (y0f <= 255.f);
    const bool vy1 = (y1f >= 0.f) && (y1f <= 255.f);
    const int xi0 = (int)fminf(fmaxf(x0f, 0.f), 255.f);
    const int xi1 = (int)fminf(fmaxf(x1f, 0.f), 255.f);
    const int yi0 = (int)fminf(fmaxf(y0f, 0.f), 255.f);
    const int yi1 = (int)fminf(fmaxf(y1f, 0.f), 255.f);
    const int i00 = yi0 * W_ + xi0, i01 = yi0 * W_ + xi1;
    const int i10 = yi1 * W_ + xi0, i11 = yi1 * W_ + xi1;
    const float w00 = ((vx0 && vy0) ? 1.f : 0.f) * (1.f - fx) * (1.f - fy);
    const float w01 = ((vx1 && vy0) ? 1.f : 0.f) * fx * (1.f - fy);
    const float w10 = ((vx0 && vy1) ? 1.f : 0.f) * (1.f - fx) * fy;
    const float w11 = ((vx1 && vy1) ? 1.f : 0.f) * fx * fy;

    const int base = b * HW;
    const uint4 u00 = imgT[base + i00], u01 = imgT[base + i01];
    const uint4 u10 = imgT[base + i10], u11 = imgT[base + i11];

    float vx = 0.f, vy = 0.f;
    #pragma unroll
    for (int c = 0; c < 8; ++c) {
        const float Q = w00 * bfex(u00, c) + w01 * bfex(u01, c)
                      + w10 * bfex(u10, c) + w11 * bfex(u11, c);
        const float r = Q - bfex(t0, c) * m;
        vx += bfex(g0, c) * r;
        vy += bfex(g1, c) * r;
    }
    const float t0a = X * vx, t4a = Y * vy;
    const float cc = t0a + t4a;
    aa[0] += t0a;      aa[1] += Y * vx;  aa[2] += vx;
    aa[3] += X * vy;   aa[4] += t4a;     aa[5] += vy;
    aa[6] -= X * cc;   aa[7] -= Y * cc;
}

// ---------------------------------------------------------------------------
// prep: R10/R11's proven 2048-block staged kernel (~15 µs), planar TG,
// plain cached stores (dispatch boundary = visibility). Blocks 0..7 also
// zero the fused kernel's flag region.
// ---------------------------------------------------------------------------
__global__ __launch_bounds__(256) void prep_kernel(
    const float* __restrict__ img, const float* __restrict__ temp,
    uint4* __restrict__ imgT, uint4* __restrict__ TGt,
    uint4* __restrict__ TGx, uint4* __restrict__ TGy,
    double* __restrict__ gramP,
    unsigned int* __restrict__ iterFlags, unsigned int* __restrict__ invHflag) {
    __shared__ float smem[8192];
    __shared__ float s15[15];
    const int b   = blockIdx.x & 7;
    const int y   = blockIdx.x >> 3;
    const int tid = threadIdx.x;

    if (blockIdx.x < 8) {   // y==0 blocks: zero flags for batch b
        for (int s = tid; s < 641; s += 256) {
            if (s < 640) iterFlags[((size_t)blockIdx.x * 640 + s) * 16] = 0u;
            else         invHflag[blockIdx.x * 16] = 0u;
        }
    }

    const int ym = (y > 0) ? y - 1 : 0;
    const int yp = (y < 255) ? y + 1 : 255;

    #pragma unroll
    for (int j = 0; j < 8; ++j) {
        const int slot = tid + 256 * j;
        const int rowid = slot >> 6, col4 = slot & 63;
        const int c = rowid >> 2, sel = rowid & 3;
        const int sy = (sel == 0) ? ym : ((sel == 2) ? yp : y);
        const float* src = ((sel == 3) ? img : temp)
                         + ((size_t)(b * K_ + c) * HW + sy * W_ + col4 * 4);
        const float4 v = *(const float4*)src;
        *(float4*)&smem[(c * 4 + sel) * 256 + col4 * 4] = v;
    }
    __syncthreads();

    const int x = tid;
    const int px = (y << 8) | x;
    const float X = (float)x - 127.5f, Y = (float)y - 127.5f;
    const int xm = (x > 0) ? x - 1 : 0;
    const int xp = (x < 255) ? x + 1 : 255;
    float Sxx = 0.f, Sxy = 0.f, Syy = 0.f;
    unsigned int imgp[4] = {0, 0, 0, 0};
    unsigned int tgp[12];
    #pragma unroll
    for (int i = 0; i < 12; ++i) tgp[i] = 0u;
    #pragma unroll
    for (int c = 0; c < 8; ++c) {
        const float* R = &smem[c * 1024];
        const float gx = 0.5f * (R[256 + xp] - R[256 + xm]);
        const float gy = 0.5f * (R[512 + x] - R[x]);
        const float tc = R[256 + x];
        const float iv = R[768 + x];
        Sxx += gx * gx; Sxy += gx * gy; Syy += gy * gy;
        const int sh = (c & 1) * 16;
        imgp[c >> 1]     |= ((unsigned int)f2bf(iv)) << sh;
        tgp[c >> 1]      |= ((unsigned int)f2bf(tc)) << sh;
        tgp[4 + (c >> 1)]|= ((unsigned int)f2bf(gx)) << sh;
        tgp[8 + (c >> 1)]|= ((unsigned int)f2bf(gy)) << sh;
    }
    const size_t gpx = (size_t)b * HW + px;
    imgT[gpx] = make_uint4(imgp[0], imgp[1], imgp[2], imgp[3]);
    TGt[gpx] = make_uint4(tgp[0], tgp[1], tgp[2],  tgp[3]);
    TGx[gpx] = make_uint4(tgp[4], tgp[5], tgp[6],  tgp[7]);
    TGy[gpx] = make_uint4(tgp[8], tgp[9], tgp[10], tgp[11]);
    __syncthreads();   // rows consumed; reuse smem for the moment reduce

    {
        const float X2 = X * X;
        const float Xp[5] = {1.f, X, X2, X2 * X, X2 * X2};
        #pragma unroll
        for (int n = 0; n < 5; ++n) {
            smem[n * 256 + tid]        = Sxx * Xp[n];
            smem[(5 + n) * 256 + tid]  = Sxy * Xp[n];
            smem[(10 + n) * 256 + tid] = Syy * Xp[n];
        }
    }
    __syncthreads();
    {
        const int e = tid >> 5, l = tid & 31;
        float v = 0.f;
        #pragma unroll
        for (int j = 0; j < 8; ++j) v += smem[e * 256 + l + 32 * j];
        v = half_reduce(v);
        if (l == 0) s15[e] = v;
    }
    if (tid < 224) {
        const int e = 8 + (tid >> 5), l = tid & 31;
        float v = 0.f;
        #pragma unroll
        for (int j = 0; j < 8; ++j) v += smem[e * 256 + l + 32 * j];
        v = half_reduce(v);
        if ((tid & 31) == 0) s15[e] = v;
    }
    __syncthreads();

    if (tid < 36) {
        const int aC[8]  = {1, 1, 1, 0, 0, 0, -1, -1};
        const int aNX[8] = {1, 0, 0, 0, 0, 0,  2,  1};
        const int aNY[8] = {0, 1, 0, 0, 0, 0,  0,  1};
        const int bC[8]  = {0, 0, 0, 1, 1, 1, -1, -1};
        const int bNX[8] = {0, 0, 0, 1, 0, 0,  1,  0};
        const int bNY[8] = {0, 0, 0, 0, 1, 0,  1,  2};
        const double Yd = (double)Y;
        const double Yp2 = Yd * Yd;
        const double Ypw[5] = {1.0, Yd, Yp2, Yp2 * Yd, Yp2 * Yp2};
        int p = 0, rem = tid;
        while (rem >= 8 - p) { rem -= 8 - p; ++p; }
        const int q = p + rem;
        double g = 0.0;
        const int ac = aC[p] * aC[q];
        if (ac) g += ac * Ypw[aNY[p] + aNY[q]] * (double)s15[aNX[p] + aNX[q]];
        const int ab1 = aC[p] * bC[q];
        if (ab1) g += ab1 * Ypw[aNY[p] + bNY[q]] * (double)s15[5 + aNX[p] + bNX[q]];
        const int ab2 = bC[p] * aC[q];
        if (ab2) g += ab2 * Ypw[bNY[p] + aNY[q]] * (double)s15[5 + bNX[p] + aNX[q]];
        const int bc = bC[p] * bC[q];
        if (bc) g += bc * Ypw[bNY[p] + bNY[q]] * (double)s15[10 + bNX[p] + bNX[q]];
        gramP[((size_t)b * 36 + tid) * 256 + y] = g;
    }
}

// ---------------------------------------------------------------------------
// fused iterations: R11's proven flag-barrier engine at DOUBLE occupancy —
// 512 blocks x 512 thr (2 px/thread), __launch_bounds__(512,4) caps VGPR at
// 128 so 2 blocks/CU (16 waves/CU, 2x R11's latency hiding) is guaranteed;
// grid 512 == 256 CU x 2 -> all resident. Same 64-blocks/batch flag barrier,
// same sP layout (64x8 partials), slim bfex pixel path (~55 live regs, fits
// even a 64-VGPR allocation without spill — proven R8). Reduction trees are
// R5's proven 512-thread forms (same absmax). All spins bounded.
// ---------------------------------------------------------------------------
__global__ __launch_bounds__(512, 4) void fused_kernel(
    const uint4* __restrict__ imgT,
    const uint4* __restrict__ TGt, const uint4* __restrict__ TGx,
    const uint4* __restrict__ TGy,
    const double* __restrict__ gramP, double* __restrict__ invHg,
    const float* __restrict__ init_param,
    float* __restrict__ sP0, float* __restrict__ sP1,
    unsigned int* __restrict__ iterFlags, unsigned int* __restrict__ invHflag,
    const int* __restrict__ max_itr, float* __restrict__ out) {
    __shared__ float red[4096];       // 16 KB block reduce (8 x 512)
    __shared__ float s8[8];
    __shared__ double sh_invH[64];
    __shared__ double sh_pd[16];      // p (0..7), dp (8..15)
    __shared__ float sh_pf[8];
    __shared__ double gpart[144];
    __shared__ double shA[64], shB[64];

    const int tid = threadIdx.x;           // 0..511
    const int b   = blockIdx.x & 7;
    const int yb  = blockIdx.x >> 3;       // 0..63, rows 4*yb..4*yb+3
    const int mi_raw = *max_itr;
    const int mi = (mi_raw > 10) ? 10 : mi_raw;

    // ---- TG slice into registers (planar loads; each thread keeps 2 px) ----
    uint4 rT[2], rGX[2], rGY[2];
    {
        const size_t base = (size_t)b * HW + (size_t)yb * 1024 + tid;
        #pragma unroll
        for (int sub = 0; sub < 2; ++sub) {
            const size_t px = base + (size_t)(sub * 512);
            rT[sub] = TGt[px]; rGX[sub] = TGx[px]; rGY[sub] = TGy[px];
        }
    }

    for (int it = 0; it < mi; ++it) {
        if (it > 0) {
            // ---- wait: 64 parallel flag polls (wave 0), no RMW chain ----
            if (tid < 64) wait_flags64(&iterFlags[(size_t)(b * 640 + (it - 1) * 64) * 16], tid);
            if (it == 1 && tid == 0) wait_count(&invHflag[b * 16], 1u);
            __syncthreads();
            if (it == 1 && tid < 64) sh_invH[tid] = cloadd(&invHg[b * 64 + tid]);
            // ---- state reconstruction (R5's 512-thread tree, proven) ----
            {
                const float* sR = ((it & 1) ? sP0 : sP1) + b * 512;
                const int e = tid >> 6, l = tid & 63;
                float v = cloadf(&sR[e * 64 + l]);
                v = wave_reduce(v);
                if (l == 0) s8[e] = v;
            }
            __syncthreads();
            if (tid < 8) {
                double nrm2 = 0.0;
                #pragma unroll
                for (int k2 = 0; k2 < 8; ++k2) {
                    const double d = sh_pd[8 + k2];
                    nrm2 += d * d;
                }
                double dpn = 0.0;
                if (tid < 6) {
                    #pragma unroll
                    for (int k2 = 0; k2 < 8; ++k2)
                        dpn += sh_invH[tid * 8 + k2] * (double)s8[k2];
                }
                const double dp2 = (sqrt(nrm2) > 1e-3) ? dpn : 0.0;
                const double pnew = sh_pd[tid] - dp2;
                sh_pd[tid]     = pnew;
                sh_pd[8 + tid] = dp2;
            }
            __syncthreads();
        } else {
            if (tid < 8) {
                sh_pd[tid]     = (double)init_param[b * 8 + tid];
                sh_pd[8 + tid] = 1.0;
            }
            __syncthreads();
        }

        const float h00 = 1.f + (float)sh_pd[0], h01 = (float)sh_pd[1], h02 = (float)sh_pd[2];
        const float h10 = (float)sh_pd[3], h11 = 1.f + (float)sh_pd[4], h12 = (float)sh_pd[5];
        const float h20 = (float)sh_pd[6], h21 = (float)sh_pd[7];

        // ---- pixel phase: 2 px/thread (R5's geometry, proven FP) ----
        float aa[8];
        #pragma unroll
        for (int e = 0; e < 8; ++e) aa[e] = 0.f;
        #pragma unroll
        for (int sub = 0; sub < 2; ++sub) {
            const int pxl = tid + 512 * sub;       // row pxl>>8, col pxl&255
            pixel_accum(imgT, rT[sub], rGX[sub], rGY[sub], b,
                        pxl & 255, yb * 4 + (pxl >> 8),
                        h00, h01, h02, h10, h11, h12, h20, h21, aa);
        }

        // ---- block reduce (R5's 512-thread tree) -> 8 coherent partials ----
        #pragma unroll
        for (int e = 0; e < 8; ++e) red[e * 512 + tid] = aa[e];
        __syncthreads();
        {
            const int e = tid >> 6, l = tid & 63;
            float v = 0.f;
            #pragma unroll
            for (int j = 0; j < 8; ++j) v += red[e * 512 + l + 64 * j];
            v = wave_reduce(v);
            if (l == 0) {
                float* sW = (it & 1) ? sP1 : sP0;
                cstoref(&sW[b * 512 + e * 64 + yb], v);
            }
        }

        // ---- arrive: drain partials, then one flag store (own line) ----
        asm volatile("s_waitcnt vmcnt(0)" ::: "memory");
        __syncthreads();
        if (tid == 0)
            cstoreu(&iterFlags[(size_t)(b * 640 + it * 64 + yb) * 16], 1u);

        // ---- iter 0, yb==0: Gram reduce + f64 Gauss-Jordan, publish invH ----
        if (it == 0 && yb == 0) {
            if (tid < 144) {
                const int e = tid >> 2, q = tid & 3;
                const double* gp = gramP + ((size_t)b * 36 + e) * 256 + q * 64;
                double acc = 0.0;
                #pragma unroll 8
                for (int i = 0; i < 64; ++i) acc += gp[i];
                gpart[tid] = acc;
            }
            __syncthreads();
            const int i = tid >> 3, j = tid & 7;
            if (tid < 64) {
                const int pp = min(i, j), qq = max(i, j);
                const int tri = 8 * pp - (pp * (pp - 1)) / 2 + (qq - pp);
                shA[tid] = gpart[tri * 4] + gpart[tri * 4 + 1]
                         + gpart[tri * 4 + 2] + gpart[tri * 4 + 3];
                shB[tid] = (i == j) ? 1.0 : 0.0;
            }
            __syncthreads();
            for (int k = 0; k < 8; ++k) {
                const double piv = shA[k * 8 + k];
                __syncthreads();
                if (tid < 64 && i == k) { shA[tid] /= piv; shB[tid] /= piv; }
                __syncthreads();
                double f = 0, ak = 0, bk = 0;
                if (tid < 64) { f = shA[i * 8 + k]; ak = shA[k * 8 + j]; bk = shB[k * 8 + j]; }
                __syncthreads();
                if (tid < 64 && i != k) { shA[tid] -= f * ak; shB[tid] -= f * bk; }
                __syncthreads();
            }
            if (tid < 64) { cstored(&invHg[b * 64 + tid], shB[tid]);
                            sh_invH[tid] = shB[tid]; }   // stash (mi==1 output)
            asm volatile("s_waitcnt vmcnt(0)" ::: "memory");
            __syncthreads();
            if (tid == 0) cstoreu(&invHflag[b * 16], 1u);
        }
    }

    // ========================= OUTPUT phase ================================
    if (yb != 0) return;                  // 8 blocks, one per batch
    if (mi <= 0) {
        if (tid < 8) out[b * 8 + tid] = init_param[b * 8 + tid];
        if (tid < 9) {
            float v = (tid < 8) ? init_param[b * 8 + tid] : 0.f;
            if (tid == 0 || tid == 4 || tid == 8) v += 1.f;
            out[64 + b * 9 + tid] = v;
        }
        return;
    }
    if (tid < 64) wait_flags64(&iterFlags[(size_t)(b * 640 + (mi - 1) * 64) * 16], tid);
    __syncthreads();
    // sh_invH present: stashed at it==0 (covers mi==1) or loaded at it==1.
    {
        const float* sb = (((mi - 1) & 1) ? sP1 : sP0) + b * 512;
        const int e = tid >> 6, l = tid & 63;
        float v = cloadf(&sb[e * 64 + l]);
        v = wave_reduce(v);
        if (l == 0) s8[e] = v;
    }
    __syncthreads();
    if (tid < 8) {
        double nrm2 = 0.0;
        #pragma unroll
        for (int k2 = 0; k2 < 8; ++k2) {
            const double d = sh_pd[8 + k2];     // dp of last iteration
            nrm2 += d * d;
        }
        double dpn = 0.0;
        if (tid < 6) {
            #pragma unroll
            for (int k2 = 0; k2 < 8; ++k2)
                dpn += sh_invH[tid * 8 + k2] * (double)s8[k2];
        }
        const double dp2 = (sqrt(nrm2) > 1e-3) ? dpn : 0.0;
        const float pf = (float)(sh_pd[tid] - dp2);
        sh_pf[tid] = pf;
        out[b * 8 + tid] = pf;
    }
    __syncthreads();
    if (tid < 9) {
        float v2 = (tid < 8) ? sh_pf[tid] : 0.f;
        if (tid == 0 || tid == 4 || tid == 8) v2 += 1.f;
        out[64 + b * 9 + tid] = v2;
    }
}

extern "C" void kernel_launch(void* const* d_in, const int* in_sizes, int n_in,
                              void* d_out, int out_size, void* d_ws, size_t ws_size,
                              hipStream_t stream) {
    const float* img        = (const float*)d_in[0];
    const float* temp       = (const float*)d_in[1];
    const float* init_param = (const float*)d_in[2];
    const int*   max_itr    = (const int*)d_in[3];
    float* out = (float*)d_out;

    char* w = (char*)d_ws;
    double* gramP = (double*)w;                        // 576 KB
    double* invHg = gramP + 73728;                     // 4 KB
    float*  sP0   = (float*)(invHg + 512);             // 16 KB
    float*  sP1   = sP0 + 4096;                        // 16 KB
    unsigned int* iterFlags = (unsigned int*)(sP1 + 4096);   // 8*640*64B = 320 KB
    unsigned int* invHflag  = iterFlags + 8 * 640 * 16;      // 8 * 64 B
    uint4* imgT   = (uint4*)(w + 1048576);             // 8.39 MB (bf16 x8 / px)
    uint4* TGt    = (uint4*)(w + 1048576 + 8388608);   // planar T / GX / GY
    uint4* TGx    = TGt + (size_t)B_ * HW;
    uint4* TGy    = TGx + (size_t)B_ * HW;

    prep_kernel<<<B_ * H_, 256, 0, stream>>>(img, temp, imgT, TGt, TGx, TGy,
                                             gramP, iterFlags, invHflag);
    // residency by construction: (512,4) caps VGPR<=128 -> 2 blocks/CU;
    // LDS ~18 KB -> 2 blocks/CU; grid 512 == 256 CU x 2 -> all resident.
    fused_kernel<<<512, 512, 0, stream>>>(imgT, TGt, TGx, TGy, gramP, invHg,
                                          init_param, sP0, sP1,
                                          iterFlags, invHflag, max_itr, out);
}

// Round 14
// 158.305 us; speedup vs baseline: 1.0107x; 1.0107x over previous
//
#include <hip/hip_runtime.h>
#include <hip/hip_bf16.h>

#define B_ 8
#define K_ 8
#define H_ 256
#define W_ 256
#define HW (H_*W_)

// ---------------------------------------------------------------------------
// helpers
// ---------------------------------------------------------------------------
__device__ __forceinline__ unsigned short f2bf(float f) {
    __hip_bfloat16 h = __float2bfloat16(f);  // RNE
    return *reinterpret_cast<unsigned short*>(&h);
}
// extract bf16 channel c (elem 2k low 16 bits, 2k+1 high) as f32; c is
// compile-time under #pragma unroll -> pure shift/mask, no unpack arrays.
__device__ __forceinline__ float bfex(uint4 u, int c) {
    const unsigned int w = (&u.x)[c >> 1];
    return __uint_as_float((c & 1) ? (w & 0xffff0000u) : (w << 16));
}
// sum within each 32-lane half of a wave; result valid in lanes 0 and 32
__device__ __forceinline__ float half_reduce(float v) {
    v += __shfl_down(v, 16, 64);
    v += __shfl_down(v, 8, 64);
    v += __shfl_down(v, 4, 64);
    v += __shfl_down(v, 2, 64);
    v += __shfl_down(v, 1, 64);
    return v;
}
// fine-grained coherent (cache-bypassing) accesses — NO L2 fences anywhere
__device__ __forceinline__ void cstoref(float* p, float v) {
    __hip_atomic_store(p, v, __ATOMIC_RELAXED, __HIP_MEMORY_SCOPE_AGENT);
}
__device__ __forceinline__ float cloadf(const float* p) {
    return __hip_atomic_load((float*)p, __ATOMIC_RELAXED, __HIP_MEMORY_SCOPE_AGENT);
}
__device__ __forceinline__ void cstored(double* p, double v) {
    __hip_atomic_store(p, v, __ATOMIC_RELAXED, __HIP_MEMORY_SCOPE_AGENT);
}
__device__ __forceinline__ double cloadd(const double* p) {
    return __hip_atomic_load((double*)p, __ATOMIC_RELAXED, __HIP_MEMORY_SCOPE_AGENT);
}
__device__ __forceinline__ void cstoreu(unsigned int* p, unsigned int v) {
    __hip_atomic_store(p, v, __ATOMIC_RELAXED, __HIP_MEMORY_SCOPE_AGENT);
}
__device__ __forceinline__ unsigned int cloadu(const unsigned int* p) {
    return __hip_atomic_load((unsigned int*)p, __ATOMIC_RELAXED, __HIP_MEMORY_SCOPE_AGENT);
}
// bounded single-flag poll (leader thread) — fast-fail, never hangs
__device__ __forceinline__ void wait_count(unsigned int* p, unsigned int target) {
    for (int i = 0; i < 20000; ++i) {
        if (cloadu(p) >= target) return;
        __builtin_amdgcn_s_sleep(1);
    }
}
// wave-parallel 64-flag wait: lanes 0..63 each poll ONE flag (own cacheline,
// stride 16 u32 = 64 B). Writers store flags in parallel (no RMW chain).
// Bounded; all lanes exit together via uniform __ballot. Proven R11.
// NOTE (R13 lesson): this 64-flag/512-block fan-in is the proven envelope;
// 128-flag/1024-block quadrupled poll contention and breached the bound.
__device__ __forceinline__ void wait_flags64(unsigned int* base, int lane) {
    for (int i = 0; i < 20000; ++i) {
        const unsigned int v = cloadu(base + lane * 16);
        if (!__ballot(v == 0u)) return;
        __builtin_amdgcn_s_sleep(1);
    }
}

// ---------------------------------------------------------------------------
// pixel geometry: warp + bilinear weights/indices for one pixel.
// Arithmetic is verbatim from the proven pixel_accum (bit-identical values).
// ---------------------------------------------------------------------------
struct PxG {
    int   i00, i01, i10, i11;
    float w00, w01, w10, w11;
    float m, X, Y;
};
__device__ __forceinline__ PxG px_setup(
    int x, int y,
    float h00, float h01, float h02, float h10, float h11, float h12,
    float h20, float h21) {
    PxG P;
    const float X = (float)x - 127.5f, Y = (float)y - 127.5f;
    const float zw = h20 * X + h21 * Y + 1.f;
    const float Xw = (h00 * X + h01 * Y + h02) / zw + 127.5f;
    const float Yw = (h10 * X + h11 * Y + h12) / zw + 127.5f;
    const float NLO = -1.f + 2.f / 256.f, NHI = 1.f - 2.f / 256.f;
    const float xn = Xw / 127.5f - 1.f, yn = Yw / 127.5f - 1.f;
    P.m = (xn > NLO && xn < NHI && yn > NLO && yn < NHI) ? 1.f : 0.f;

    const float x0f = floorf(Xw), y0f = floorf(Yw);
    const float fx = Xw - x0f, fy = Yw - y0f;
    const float x1f = x0f + 1.f, y1f = y0f + 1.f;
    const bool vx0 = (x0f >= 0.f) && (x0f <= 255.f);
    const bool vx1 = (x1f >= 0.f) && (x1f <= 255.f);
    const bool vy0 = (y0f >= 0.f) && (y0f <= 255.f);
    const bool vy1 = (y1f >= 0.f) && (y1f <= 255.f);
    const int xi0 = (int)fminf(fmaxf(x0f, 0.f), 255.f);
    const int xi1 = (int)fminf(fmaxf(x1f, 0.f), 255.f);
    const int yi0 = (int)fminf(fmaxf(y0f, 0.f), 255.f);
    const int yi1 = (int)fminf(fmaxf(y1f, 0.f), 255.f);
    P.i00 = yi0 * W_ + xi0; P.i01 = yi0 * W_ + xi1;
    P.i10 = yi1 * W_ + xi0; P.i11 = yi1 * W_ + xi1;
    P.w00 = ((vx0 && vy0) ? 1.f : 0.f) * (1.f - fx) * (1.f - fy);
    P.w01 = ((vx1 && vy0) ? 1.f : 0.f) * fx * (1.f - fy);
    P.w10 = ((vx0 && vy1) ? 1.f : 0.f) * (1.f - fx) * fy;
    P.w11 = ((vx1 && vy1) ? 1.f : 0.f) * fx * fy;
    P.X = X; P.Y = Y;
    return P;
}
__device__ __forceinline__ void px_consume(
    const PxG& P, uint4 u00, uint4 u01, uint4 u10, uint4 u11,
    uint4 t0, uint4 g0, uint4 g1, float* aa) {
    float vx = 0.f, vy = 0.f;
    #pragma unroll
    for (int c = 0; c < 8; ++c) {
        const float Q = P.w00 * bfex(u00, c) + P.w01 * bfex(u01, c)
                      + P.w10 * bfex(u10, c) + P.w11 * bfex(u11, c);
        const float r = Q - bfex(t0, c) * P.m;
        vx += bfex(g0, c) * r;
        vy += bfex(g1, c) * r;
    }
    const float t0a = P.X * vx, t4a = P.Y * vy;
    const float cc = t0a + t4a;
    aa[0] += t0a;        aa[1] += P.Y * vx;  aa[2] += vx;
    aa[3] += P.X * vy;   aa[4] += t4a;       aa[5] += vy;
    aa[6] -= P.X * cc;   aa[7] -= P.Y * cc;
}

// ---------------------------------------------------------------------------
// prep: proven 2048-block staged kernel (~15 µs), planar TG, plain cached
// stores (dispatch boundary = visibility). Blocks 0..7 zero the flag region.
// ---------------------------------------------------------------------------
__global__ __launch_bounds__(256) void prep_kernel(
    const float* __restrict__ img, const float* __restrict__ temp,
    uint4* __restrict__ imgT, uint4* __restrict__ TGt,
    uint4* __restrict__ TGx, uint4* __restrict__ TGy,
    double* __restrict__ gramP,
    unsigned int* __restrict__ iterFlags, unsigned int* __restrict__ invHflag) {
    __shared__ float smem[8192];
    __shared__ float s15[15];
    const int b   = blockIdx.x & 7;
    const int y   = blockIdx.x >> 3;
    const int tid = threadIdx.x;

    if (blockIdx.x < 8) {   // y==0 blocks: zero flags for batch b
        for (int s = tid; s < 641; s += 256) {
            if (s < 640) iterFlags[((size_t)blockIdx.x * 640 + s) * 16] = 0u;
            else         invHflag[blockIdx.x * 16] = 0u;
        }
    }

    const int ym = (y > 0) ? y - 1 : 0;
    const int yp = (y < 255) ? y + 1 : 255;

    #pragma unroll
    for (int j = 0; j < 8; ++j) {
        const int slot = tid + 256 * j;
        const int rowid = slot >> 6, col4 = slot & 63;
        const int c = rowid >> 2, sel = rowid & 3;
        const int sy = (sel == 0) ? ym : ((sel == 2) ? yp : y);
        const float* src = ((sel == 3) ? img : temp)
                         + ((size_t)(b * K_ + c) * HW + sy * W_ + col4 * 4);
        const float4 v = *(const float4*)src;
        *(float4*)&smem[(c * 4 + sel) * 256 + col4 * 4] = v;
    }
    __syncthreads();

    const int x = tid;
    const int px = (y << 8) | x;
    const float X = (float)x - 127.5f, Y = (float)y - 127.5f;
    const int xm = (x > 0) ? x - 1 : 0;
    const int xp = (x < 255) ? x + 1 : 255;
    float Sxx = 0.f, Sxy = 0.f, Syy = 0.f;
    unsigned int imgp[4] = {0, 0, 0, 0};
    unsigned int tgp[12];
    #pragma unroll
    for (int i = 0; i < 12; ++i) tgp[i] = 0u;
    #pragma unroll
    for (int c = 0; c < 8; ++c) {
        const float* R = &smem[c * 1024];
        const float gx = 0.5f * (R[256 + xp] - R[256 + xm]);
        const float gy = 0.5f * (R[512 + x] - R[x]);
        const float tc = R[256 + x];
        const float iv = R[768 + x];
        Sxx += gx * gx; Sxy += gx * gy; Syy += gy * gy;
        const int sh = (c & 1) * 16;
        imgp[c >> 1]     |= ((unsigned int)f2bf(iv)) << sh;
        tgp[c >> 1]      |= ((unsigned int)f2bf(tc)) << sh;
        tgp[4 + (c >> 1)]|= ((unsigned int)f2bf(gx)) << sh;
        tgp[8 + (c >> 1)]|= ((unsigned int)f2bf(gy)) << sh;
    }
    const size_t gpx = (size_t)b * HW + px;
    imgT[gpx] = make_uint4(imgp[0], imgp[1], imgp[2], imgp[3]);
    TGt[gpx] = make_uint4(tgp[0], tgp[1], tgp[2],  tgp[3]);
    TGx[gpx] = make_uint4(tgp[4], tgp[5], tgp[6],  tgp[7]);
    TGy[gpx] = make_uint4(tgp[8], tgp[9], tgp[10], tgp[11]);
    __syncthreads();   // rows consumed; reuse smem for the moment reduce

    {
        const float X2 = X * X;
        const float Xp[5] = {1.f, X, X2, X2 * X, X2 * X2};
        #pragma unroll
        for (int n = 0; n < 5; ++n) {
            smem[n * 256 + tid]        = Sxx * Xp[n];
            smem[(5 + n) * 256 + tid]  = Sxy * Xp[n];
            smem[(10 + n) * 256 + tid] = Syy * Xp[n];
        }
    }
    __syncthreads();
    {
        const int e = tid >> 5, l = tid & 31;
        float v = 0.f;
        #pragma unroll
        for (int j = 0; j < 8; ++j) v += smem[e * 256 + l + 32 * j];
        v = half_reduce(v);
        if (l == 0) s15[e] = v;
    }
    if (tid < 224) {
        const int e = 8 + (tid >> 5), l = tid & 31;
        float v = 0.f;
        #pragma unroll
        for (int j = 0; j < 8; ++j) v += smem[e * 256 + l + 32 * j];
        v = half_reduce(v);
        if ((tid & 31) == 0) s15[e] = v;
    }
    __syncthreads();

    if (tid < 36) {
        const int aC[8]  = {1, 1, 1, 0, 0, 0, -1, -1};
        const int aNX[8] = {1, 0, 0, 0, 0, 0,  2,  1};
        const int aNY[8] = {0, 1, 0, 0, 0, 0,  0,  1};
        const int bC[8]  = {0, 0, 0, 1, 1, 1, -1, -1};
        const int bNX[8] = {0, 0, 0, 1, 0, 0,  1,  0};
        const int bNY[8] = {0, 0, 0, 0, 1, 0,  1,  2};
        const double Yd = (double)Y;
        const double Yp2 = Yd * Yd;
        const double Ypw[5] = {1.0, Yd, Yp2, Yp2 * Yd, Yp2 * Yp2};
        int p = 0, rem = tid;
        while (rem >= 8 - p) { rem -= 8 - p; ++p; }
        const int q = p + rem;
        double g = 0.0;
        const int ac = aC[p] * aC[q];
        if (ac) g += ac * Ypw[aNY[p] + aNY[q]] * (double)s15[aNX[p] + aNX[q]];
        const int ab1 = aC[p] * bC[q];
        if (ab1) g += ab1 * Ypw[aNY[p] + bNY[q]] * (double)s15[5 + aNX[p] + bNX[q]];
        const int ab2 = bC[p] * aC[q];
        if (ab2) g += ab2 * Ypw[bNY[p] + aNY[q]] * (double)s15[5 + bNX[p] + aNX[q]];
        const int bc = bC[p] * bC[q];
        if (bc) g += bc * Ypw[bNY[p] + bNY[q]] * (double)s15[10 + bNX[p] + bNX[q]];
        gramP[((size_t)b * 36 + tid) * 256 + y] = g;
    }
}

// ---------------------------------------------------------------------------
// fused iterations: R11's proven engine VERBATIM (512 blocks x 256 thr,
// __launch_bounds__(256,2), 64-flag barriers, TG in registers, output folded
// in) with ONE change: the pixel phase issues gathers in PAIRS (8 loads in
// flight before consumption) instead of per-pixel (4). Bit-identical
// arithmetic, same accumulation order — cannot fail validation; only the
// load schedule changes (2x MLP per wave to hide L2 gather latency).
// ---------------------------------------------------------------------------
__global__ __launch_bounds__(256, 2) void fused_kernel(
    const uint4* __restrict__ imgT,
    const uint4* __restrict__ TGt, const uint4* __restrict__ TGx,
    const uint4* __restrict__ TGy,
    const double* __restrict__ gramP, double* __restrict__ invHg,
    const float* __restrict__ init_param,
    float* __restrict__ sP0, float* __restrict__ sP1,
    unsigned int* __restrict__ iterFlags, unsigned int* __restrict__ invHflag,
    const int* __restrict__ max_itr, float* __restrict__ out) {
    __shared__ float red[2048];
    __shared__ float s8[8];
    __shared__ double sh_invH[64];
    __shared__ double sh_pd[16];      // p (0..7), dp (8..15)
    __shared__ float sh_pf[8];
    __shared__ double gpart[144];
    __shared__ double shA[64], shB[64];

    const int tid = threadIdx.x;
    const int b   = blockIdx.x & 7;
    const int yb  = blockIdx.x >> 3;       // 0..63, rows 4*yb..4*yb+3
    const int mi_raw = *max_itr;
    const int mi = (mi_raw > 10) ? 10 : mi_raw;

    // ---- TG slice into registers (planar loads; each thread keeps 4 px) ----
    uint4 rT[4], rGX[4], rGY[4];
    {
        const size_t base = (size_t)b * HW + (size_t)yb * 1024 + tid;
        #pragma unroll
        for (int sub = 0; sub < 4; ++sub) {
            const size_t px = base + (size_t)(sub * 256);
            rT[sub] = TGt[px]; rGX[sub] = TGx[px]; rGY[sub] = TGy[px];
        }
    }

    for (int it = 0; it < mi; ++it) {
        if (it > 0) {
            // ---- wait: 64 parallel flag polls (wave 0), no RMW chain ----
            if (tid < 64) wait_flags64(&iterFlags[(size_t)(b * 640 + (it - 1) * 64) * 16], tid);
            if (it == 1 && tid == 0) wait_count(&invHflag[b * 16], 1u);
            __syncthreads();
            if (it == 1 && tid < 64) sh_invH[tid] = cloadd(&invHg[b * 64 + tid]);
            // ---- state reconstruction (coherent reads; identical FP/block) ----
            {
                const float* sR = ((it & 1) ? sP0 : sP1) + b * 512;
                const int e = tid >> 5, l = tid & 31;
                float v = cloadf(&sR[e * 64 + l]) + cloadf(&sR[e * 64 + 32 + l]);
                v = half_reduce(v);
                if (l == 0) s8[e] = v;
            }
            __syncthreads();
            if (tid < 8) {
                double nrm2 = 0.0;
                #pragma unroll
                for (int k2 = 0; k2 < 8; ++k2) {
                    const double d = sh_pd[8 + k2];
                    nrm2 += d * d;
                }
                double dpn = 0.0;
                if (tid < 6) {
                    #pragma unroll
                    for (int k2 = 0; k2 < 8; ++k2)
                        dpn += sh_invH[tid * 8 + k2] * (double)s8[k2];
                }
                const double dp2 = (sqrt(nrm2) > 1e-3) ? dpn : 0.0;
                const double pnew = sh_pd[tid] - dp2;
                sh_pd[tid]     = pnew;
                sh_pd[8 + tid] = dp2;
            }
            __syncthreads();
        } else {
            if (tid < 8) {
                sh_pd[tid]     = (double)init_param[b * 8 + tid];
                sh_pd[8 + tid] = 1.0;
            }
            __syncthreads();
        }

        const float h00 = 1.f + (float)sh_pd[0], h01 = (float)sh_pd[1], h02 = (float)sh_pd[2];
        const float h10 = (float)sh_pd[3], h11 = 1.f + (float)sh_pd[4], h12 = (float)sh_pd[5];
        const float h20 = (float)sh_pd[6], h21 = (float)sh_pd[7];

        // ---- pixel phase: 4 px/thread in PAIRS (8 gathers in flight) ----
        float aa[8];
        #pragma unroll
        for (int e = 0; e < 8; ++e) aa[e] = 0.f;
        const int base = b * HW;
        #pragma unroll
        for (int sub = 0; sub < 4; sub += 2) {
            const PxG A = px_setup(tid, yb * 4 + sub,
                                   h00, h01, h02, h10, h11, h12, h20, h21);
            const PxG B = px_setup(tid, yb * 4 + sub + 1,
                                   h00, h01, h02, h10, h11, h12, h20, h21);
            // issue all 8 gathers before any consumption
            const uint4 uA00 = imgT[base + A.i00], uA01 = imgT[base + A.i01];
            const uint4 uA10 = imgT[base + A.i10], uA11 = imgT[base + A.i11];
            const uint4 uB00 = imgT[base + B.i00], uB01 = imgT[base + B.i01];
            const uint4 uB10 = imgT[base + B.i10], uB11 = imgT[base + B.i11];
            px_consume(A, uA00, uA01, uA10, uA11,
                       rT[sub], rGX[sub], rGY[sub], aa);
            px_consume(B, uB00, uB01, uB10, uB11,
                       rT[sub + 1], rGX[sub + 1], rGY[sub + 1], aa);
        }

        // ---- block reduce -> 8 coherent partial stores per block ----
        #pragma unroll
        for (int e = 0; e < 8; ++e) red[e * 256 + tid] = aa[e];
        __syncthreads();
        {
            const int e = tid >> 5, l = tid & 31;
            float v = 0.f;
            #pragma unroll
            for (int j = 0; j < 8; ++j) v += red[e * 256 + l + 32 * j];
            v = half_reduce(v);
            if (l == 0) {
                float* sW = (it & 1) ? sP1 : sP0;
                cstoref(&sW[b * 512 + e * 64 + yb], v);
            }
        }

        // ---- arrive: drain partials, then one flag store (own line) ----
        asm volatile("s_waitcnt vmcnt(0)" ::: "memory");
        __syncthreads();
        if (tid == 0)
            cstoreu(&iterFlags[(size_t)(b * 640 + it * 64 + yb) * 16], 1u);

        // ---- iter 0, yb==0: Gram reduce + f64 Gauss-Jordan, publish invH ----
        if (it == 0 && yb == 0) {
            if (tid < 144) {
                const int e = tid >> 2, q = tid & 3;
                const double* gp = gramP + ((size_t)b * 36 + e) * 256 + q * 64;
                double acc = 0.0;
                #pragma unroll 8
                for (int i = 0; i < 64; ++i) acc += gp[i];
                gpart[tid] = acc;
            }
            __syncthreads();
            const int i = tid >> 3, j = tid & 7;
            if (tid < 64) {
                const int pp = min(i, j), qq = max(i, j);
                const int tri = 8 * pp - (pp * (pp - 1)) / 2 + (qq - pp);
                shA[tid] = gpart[tri * 4] + gpart[tri * 4 + 1]
                         + gpart[tri * 4 + 2] + gpart[tri * 4 + 3];
                shB[tid] = (i == j) ? 1.0 : 0.0;
            }
            __syncthreads();
            for (int k = 0; k < 8; ++k) {
                const double piv = shA[k * 8 + k];
                __syncthreads();
                if (tid < 64 && i == k) { shA[tid] /= piv; shB[tid] /= piv; }
                __syncthreads();
                double f = 0, ak = 0, bk = 0;
                if (tid < 64) { f = shA[i * 8 + k]; ak = shA[k * 8 + j]; bk = shB[k * 8 + j]; }
                __syncthreads();
                if (tid < 64 && i != k) { shA[tid] -= f * ak; shB[tid] -= f * bk; }
                __syncthreads();
            }
            if (tid < 64) { cstored(&invHg[b * 64 + tid], shB[tid]);
                            sh_invH[tid] = shB[tid]; }   // stash (mi==1 output)
            asm volatile("s_waitcnt vmcnt(0)" ::: "memory");
            __syncthreads();
            if (tid == 0) cstoreu(&invHflag[b * 16], 1u);
        }
    }

    // ========================= OUTPUT phase ================================
    if (yb != 0) return;                  // 8 blocks, one per batch
    if (mi <= 0) {
        if (tid < 8) out[b * 8 + tid] = init_param[b * 8 + tid];
        if (tid < 9) {
            float v = (tid < 8) ? init_param[b * 8 + tid] : 0.f;
            if (tid == 0 || tid == 4 || tid == 8) v += 1.f;
            out[64 + b * 9 + tid] = v;
        }
        return;
    }
    if (tid < 64) wait_flags64(&iterFlags[(size_t)(b * 640 + (mi - 1) * 64) * 16], tid);
    __syncthreads();
    // sh_invH present: stashed at it==0 (covers mi==1) or loaded at it==1.
    {
        const float* sb = (((mi - 1) & 1) ? sP1 : sP0) + b * 512;
        const int e = tid >> 5, l = tid & 31;
        float v = cloadf(&sb[e * 64 + l]) + cloadf(&sb[e * 64 + 32 + l]);
        v = half_reduce(v);
        if (l == 0) s8[e] = v;
    }
    __syncthreads();
    if (tid < 8) {
        double nrm2 = 0.0;
        #pragma unroll
        for (int k2 = 0; k2 < 8; ++k2) {
            const double d = sh_pd[8 + k2];     // dp of last iteration
            nrm2 += d * d;
        }
        double dpn = 0.0;
        if (tid < 6) {
            #pragma unroll
            for (int k2 = 0; k2 < 8; ++k2)
                dpn += sh_invH[tid * 8 + k2] * (double)s8[k2];
        }
        const double dp2 = (sqrt(nrm2) > 1e-3) ? dpn : 0.0;
        const float pf = (float)(sh_pd[tid] - dp2);
        sh_pf[tid] = pf;
        out[b * 8 + tid] = pf;
    }
    __syncthreads();
    if (tid < 9) {
        float v2 = (tid < 8) ? sh_pf[tid] : 0.f;
        if (tid == 0 || tid == 4 || tid == 8) v2 += 1.f;
        out[64 + b * 9 + tid] = v2;
    }
}

extern "C" void kernel_launch(void* const* d_in, const int* in_sizes, int n_in,
                              void* d_out, int out_size, void* d_ws, size_t ws_size,
                              hipStream_t stream) {
    const float* img        = (const float*)d_in[0];
    const float* temp       = (const float*)d_in[1];
    const float* init_param = (const float*)d_in[2];
    const int*   max_itr    = (const int*)d_in[3];
    float* out = (float*)d_out;

    char* w = (char*)d_ws;
    double* gramP = (double*)w;                        // 576 KB
    double* invHg = gramP + 73728;                     // 4 KB
    float*  sP0   = (float*)(invHg + 512);             // 16 KB
    float*  sP1   = sP0 + 4096;                        // 16 KB
    unsigned int* iterFlags = (unsigned int*)(sP1 + 4096);   // 8*640*64B = 320 KB
    unsigned int* invHflag  = iterFlags + 8 * 640 * 16;      // 8 * 64 B
    uint4* imgT   = (uint4*)(w + 1048576);             // 8.39 MB (bf16 x8 / px)
    uint4* TGt    = (uint4*)(w + 1048576 + 8388608);   // planar T / GX / GY
    uint4* TGx    = TGt + (size_t)B_ * HW;
    uint4* TGy    = TGx + (size_t)B_ * HW;

    prep_kernel<<<B_ * H_, 256, 0, stream>>>(img, temp, imgT, TGt, TGx, TGy,
                                             gramP, iterFlags, invHflag);
    // 512 blocks == 256 CU x 2: residency by capacity (LDS ~11 KB; (256,2)
    // caps VGPR at 256 -> 2 blocks/CU always fit). Proven R11 envelope.
    fused_kernel<<<512, 256, 0, stream>>>(imgT, TGt, TGx, TGy, gramP, invHg,
                                          init_param, sP0, sP1,
                                          iterFlags, invHflag, max_itr, out);
}

// Round 15
// 157.351 us; speedup vs baseline: 1.0169x; 1.0061x over previous
//
#include <hip/hip_runtime.h>
#include <hip/hip_bf16.h>

#define B_ 8
#define K_ 8
#define H_ 256
#define W_ 256
#define HW (H_*W_)

// ---------------------------------------------------------------------------
// helpers
// ---------------------------------------------------------------------------
__device__ __forceinline__ unsigned short f2bf(float f) {
    __hip_bfloat16 h = __float2bfloat16(f);  // RNE
    return *reinterpret_cast<unsigned short*>(&h);
}
// extract bf16 channel c (elem 2k low 16 bits, 2k+1 high) as f32; c is
// compile-time under #pragma unroll -> pure shift/mask, no unpack arrays.
__device__ __forceinline__ float bfex(uint4 u, int c) {
    const unsigned int w = (&u.x)[c >> 1];
    return __uint_as_float((c & 1) ? (w & 0xffff0000u) : (w << 16));
}
// sum within each 32-lane half of a wave; result valid in lanes 0 and 32
__device__ __forceinline__ float half_reduce(float v) {
    v += __shfl_down(v, 16, 64);
    v += __shfl_down(v, 8, 64);
    v += __shfl_down(v, 4, 64);
    v += __shfl_down(v, 2, 64);
    v += __shfl_down(v, 1, 64);
    return v;
}
// fine-grained coherent (cache-bypassing) accesses — NO L2 fences anywhere
__device__ __forceinline__ void cstoref(float* p, float v) {
    __hip_atomic_store(p, v, __ATOMIC_RELAXED, __HIP_MEMORY_SCOPE_AGENT);
}
__device__ __forceinline__ float cloadf(const float* p) {
    return __hip_atomic_load((float*)p, __ATOMIC_RELAXED, __HIP_MEMORY_SCOPE_AGENT);
}
__device__ __forceinline__ void cstored(double* p, double v) {
    __hip_atomic_store(p, v, __ATOMIC_RELAXED, __HIP_MEMORY_SCOPE_AGENT);
}
__device__ __forceinline__ double cloadd(const double* p) {
    return __hip_atomic_load((double*)p, __ATOMIC_RELAXED, __HIP_MEMORY_SCOPE_AGENT);
}
__device__ __forceinline__ void cstoreu(unsigned int* p, unsigned int v) {
    __hip_atomic_store(p, v, __ATOMIC_RELAXED, __HIP_MEMORY_SCOPE_AGENT);
}
__device__ __forceinline__ unsigned int cloadu(const unsigned int* p) {
    return __hip_atomic_load((unsigned int*)p, __ATOMIC_RELAXED, __HIP_MEMORY_SCOPE_AGENT);
}
// bounded single-flag poll (leader thread) — fast-fail, never hangs
__device__ __forceinline__ void wait_count(unsigned int* p, unsigned int target) {
    for (int i = 0; i < 20000; ++i) {
        if (cloadu(p) >= target) return;
        __builtin_amdgcn_s_sleep(1);
    }
}
// wave-parallel 64-flag wait: lanes 0..63 each poll ONE flag (own cacheline,
// stride 16 u32 = 64 B). Writers store flags in parallel (no RMW chain — the
// serialized 64-RMW arrival was ~4.8 µs/iter in the counter-barrier design).
// Bounded; all lanes exit together via uniform __ballot.
// NOTE (R13 lesson): 64-flag/512-block fan-in is the proven envelope;
// 128-flag/1024-block quadrupled poll contention and breached the bound.
__device__ __forceinline__ void wait_flags64(unsigned int* base, int lane) {
    for (int i = 0; i < 20000; ++i) {
        const unsigned int v = cloadu(base + lane * 16);
        if (!__ballot(v == 0u)) return;
        __builtin_amdgcn_s_sleep(1);
    }
}

// per-pixel warp + bilinear + residual; TG fragment in registers (bfex form)
__device__ __forceinline__ void pixel_accum(
    const uint4* __restrict__ imgT,
    const uint4 t0, const uint4 g0, const uint4 g1,
    int b, int x, int y,
    float h00, float h01, float h02, float h10, float h11, float h12,
    float h20, float h21, float* aa) {
    const float X = (float)x - 127.5f, Y = (float)y - 127.5f;
    const float zw = h20 * X + h21 * Y + 1.f;
    const float Xw = (h00 * X + h01 * Y + h02) / zw + 127.5f;
    const float Yw = (h10 * X + h11 * Y + h12) / zw + 127.5f;
    const float NLO = -1.f + 2.f / 256.f, NHI = 1.f - 2.f / 256.f;
    const float xn = Xw / 127.5f - 1.f, yn = Yw / 127.5f - 1.f;
    const float m = (xn > NLO && xn < NHI && yn > NLO && yn < NHI) ? 1.f : 0.f;

    const float x0f = floorf(Xw), y0f = floorf(Yw);
    const float fx = Xw - x0f, fy = Yw - y0f;
    const float x1f = x0f + 1.f, y1f = y0f + 1.f;
    const bool vx0 = (x0f >= 0.f) && (x0f <= 255.f);
    const bool vx1 = (x1f >= 0.f) && (x1f <= 255.f);
    const bool vy0 = (y0f >= 0.f) && (y0f <= 255.f);
    const bool vy1 = (y1f >= 0.f) && (y1f <= 255.f);
    const int xi0 = (int)fminf(fmaxf(x0f, 0.f), 255.f);
    const int xi1 = (int)fminf(fmaxf(x1f, 0.f), 255.f);
    const int yi0 = (int)fminf(fmaxf(y0f, 0.f), 255.f);
    const int yi1 = (int)fminf(fmaxf(y1f, 0.f), 255.f);
    const int i00 = yi0 * W_ + xi0, i01 = yi0 * W_ + xi1;
    const int i10 = yi1 * W_ + xi0, i11 = yi1 * W_ + xi1;
    const float w00 = ((vx0 && vy0) ? 1.f : 0.f) * (1.f - fx) * (1.f - fy);
    const float w01 = ((vx1 && vy0) ? 1.f : 0.f) * fx * (1.f - fy);
    const float w10 = ((vx0 && vy1) ? 1.f : 0.f) * (1.f - fx) * fy;
    const float w11 = ((vx1 && vy1) ? 1.f : 0.f) * fx * fy;

    const int base = b * HW;
    const uint4 u00 = imgT[base + i00], u01 = imgT[base + i01];
    const uint4 u10 = imgT[base + i10], u11 = imgT[base + i11];

    float vx = 0.f, vy = 0.f;
    #pragma unroll
    for (int c = 0; c < 8; ++c) {
        const float Q = w00 * bfex(u00, c) + w01 * bfex(u01, c)
                      + w10 * bfex(u10, c) + w11 * bfex(u11, c);
        const float r = Q - bfex(t0, c) * m;
        vx += bfex(g0, c) * r;
        vy += bfex(g1, c) * r;
    }
    const float t0a = X * vx, t4a = Y * vy;
    const float cc = t0a + t4a;
    aa[0] += t0a;      aa[1] += Y * vx;  aa[2] += vx;
    aa[3] += X * vy;   aa[4] += t4a;     aa[5] += vy;
    aa[6] -= X * cc;   aa[7] -= Y * cc;
}

// ---------------------------------------------------------------------------
// prep: proven 2048-block staged kernel (~15 µs), planar TG, plain cached
// stores (dispatch boundary = visibility). Blocks 0..7 zero the flag region.
// ---------------------------------------------------------------------------
__global__ __launch_bounds__(256) void prep_kernel(
    const float* __restrict__ img, const float* __restrict__ temp,
    uint4* __restrict__ imgT, uint4* __restrict__ TGt,
    uint4* __restrict__ TGx, uint4* __restrict__ TGy,
    double* __restrict__ gramP,
    unsigned int* __restrict__ iterFlags, unsigned int* __restrict__ invHflag) {
    __shared__ float smem[8192];
    __shared__ float s15[15];
    const int b   = blockIdx.x & 7;
    const int y   = blockIdx.x >> 3;
    const int tid = threadIdx.x;

    if (blockIdx.x < 8) {   // y==0 blocks: zero flags for batch b
        for (int s = tid; s < 641; s += 256) {
            if (s < 640) iterFlags[((size_t)blockIdx.x * 640 + s) * 16] = 0u;
            else         invHflag[blockIdx.x * 16] = 0u;
        }
    }

    const int ym = (y > 0) ? y - 1 : 0;
    const int yp = (y < 255) ? y + 1 : 255;

    #pragma unroll
    for (int j = 0; j < 8; ++j) {
        const int slot = tid + 256 * j;
        const int rowid = slot >> 6, col4 = slot & 63;
        const int c = rowid >> 2, sel = rowid & 3;
        const int sy = (sel == 0) ? ym : ((sel == 2) ? yp : y);
        const float* src = ((sel == 3) ? img : temp)
                         + ((size_t)(b * K_ + c) * HW + sy * W_ + col4 * 4);
        const float4 v = *(const float4*)src;
        *(float4*)&smem[(c * 4 + sel) * 256 + col4 * 4] = v;
    }
    __syncthreads();

    const int x = tid;
    const int px = (y << 8) | x;
    const float X = (float)x - 127.5f, Y = (float)y - 127.5f;
    const int xm = (x > 0) ? x - 1 : 0;
    const int xp = (x < 255) ? x + 1 : 255;
    float Sxx = 0.f, Sxy = 0.f, Syy = 0.f;
    unsigned int imgp[4] = {0, 0, 0, 0};
    unsigned int tgp[12];
    #pragma unroll
    for (int i = 0; i < 12; ++i) tgp[i] = 0u;
    #pragma unroll
    for (int c = 0; c < 8; ++c) {
        const float* R = &smem[c * 1024];
        const float gx = 0.5f * (R[256 + xp] - R[256 + xm]);
        const float gy = 0.5f * (R[512 + x] - R[x]);
        const float tc = R[256 + x];
        const float iv = R[768 + x];
        Sxx += gx * gx; Sxy += gx * gy; Syy += gy * gy;
        const int sh = (c & 1) * 16;
        imgp[c >> 1]     |= ((unsigned int)f2bf(iv)) << sh;
        tgp[c >> 1]      |= ((unsigned int)f2bf(tc)) << sh;
        tgp[4 + (c >> 1)]|= ((unsigned int)f2bf(gx)) << sh;
        tgp[8 + (c >> 1)]|= ((unsigned int)f2bf(gy)) << sh;
    }
    const size_t gpx = (size_t)b * HW + px;
    imgT[gpx] = make_uint4(imgp[0], imgp[1], imgp[2], imgp[3]);
    TGt[gpx] = make_uint4(tgp[0], tgp[1], tgp[2],  tgp[3]);
    TGx[gpx] = make_uint4(tgp[4], tgp[5], tgp[6],  tgp[7]);
    TGy[gpx] = make_uint4(tgp[8], tgp[9], tgp[10], tgp[11]);
    __syncthreads();   // rows consumed; reuse smem for the moment reduce

    {
        const float X2 = X * X;
        const float Xp[5] = {1.f, X, X2, X2 * X, X2 * X2};
        #pragma unroll
        for (int n = 0; n < 5; ++n) {
            smem[n * 256 + tid]        = Sxx * Xp[n];
            smem[(5 + n) * 256 + tid]  = Sxy * Xp[n];
            smem[(10 + n) * 256 + tid] = Syy * Xp[n];
        }
    }
    __syncthreads();
    {
        const int e = tid >> 5, l = tid & 31;
        float v = 0.f;
        #pragma unroll
        for (int j = 0; j < 8; ++j) v += smem[e * 256 + l + 32 * j];
        v = half_reduce(v);
        if (l == 0) s15[e] = v;
    }
    if (tid < 224) {
        const int e = 8 + (tid >> 5), l = tid & 31;
        float v = 0.f;
        #pragma unroll
        for (int j = 0; j < 8; ++j) v += smem[e * 256 + l + 32 * j];
        v = half_reduce(v);
        if ((tid & 31) == 0) s15[e] = v;
    }
    __syncthreads();

    if (tid < 36) {
        const int aC[8]  = {1, 1, 1, 0, 0, 0, -1, -1};
        const int aNX[8] = {1, 0, 0, 0, 0, 0,  2,  1};
        const int aNY[8] = {0, 1, 0, 0, 0, 0,  0,  1};
        const int bC[8]  = {0, 0, 0, 1, 1, 1, -1, -1};
        const int bNX[8] = {0, 0, 0, 1, 0, 0,  1,  0};
        const int bNY[8] = {0, 0, 0, 0, 1, 0,  1,  2};
        const double Yd = (double)Y;
        const double Yp2 = Yd * Yd;
        const double Ypw[5] = {1.0, Yd, Yp2, Yp2 * Yd, Yp2 * Yp2};
        int p = 0, rem = tid;
        while (rem >= 8 - p) { rem -= 8 - p; ++p; }
        const int q = p + rem;
        double g = 0.0;
        const int ac = aC[p] * aC[q];
        if (ac) g += ac * Ypw[aNY[p] + aNY[q]] * (double)s15[aNX[p] + aNX[q]];
        const int ab1 = aC[p] * bC[q];
        if (ab1) g += ab1 * Ypw[aNY[p] + bNY[q]] * (double)s15[5 + aNX[p] + bNX[q]];
        const int ab2 = bC[p] * aC[q];
        if (ab2) g += ab2 * Ypw[bNY[p] + aNY[q]] * (double)s15[5 + bNX[p] + aNX[q]];
        const int bc = bC[p] * bC[q];
        if (bc) g += bc * Ypw[bNY[p] + bNY[q]] * (double)s15[10 + bNX[p] + bNX[q]];
        gramP[((size_t)b * 36 + tid) * 256 + y] = g;
    }
}

// ---------------------------------------------------------------------------
// fused iterations: R11's proven flag-barrier engine VERBATIM — the session's
// best measured configuration (156.25 µs total; fused 73.6 µs; VGPR 100; no
// spills). 512 blocks x 256 thr, __launch_bounds__(256,2), 4 px/thread, TG
// in registers, 64 parallel own-line flag stores per (batch,iter); wait =
// wave-parallel 64-flag ballot poll. invH on (yb==0) during iter 0 behind a
// single-writer flag. Output folded in. All spins bounded (fail-soft).
//
// Structural plateau documented R4-R14: min-waves>=4 launch bounds clamp the
// allocator to 64 VGPR and spill (R4/5/12); 1024-block barriers breach the
// fan-in envelope (R13); pair-issued gathers are neutral (R14). 8 waves/CU
// is the max good-codegen occupancy for this engine.
// ---------------------------------------------------------------------------
__global__ __launch_bounds__(256, 2) void fused_kernel(
    const uint4* __restrict__ imgT,
    const uint4* __restrict__ TGt, const uint4* __restrict__ TGx,
    const uint4* __restrict__ TGy,
    const double* __restrict__ gramP, double* __restrict__ invHg,
    const float* __restrict__ init_param,
    float* __restrict__ sP0, float* __restrict__ sP1,
    unsigned int* __restrict__ iterFlags, unsigned int* __restrict__ invHflag,
    const int* __restrict__ max_itr, float* __restrict__ out) {
    __shared__ float red[2048];
    __shared__ float s8[8];
    __shared__ double sh_invH[64];
    __shared__ double sh_pd[16];      // p (0..7), dp (8..15)
    __shared__ float sh_pf[8];
    __shared__ double gpart[144];
    __shared__ double shA[64], shB[64];

    const int tid = threadIdx.x;
    const int b   = blockIdx.x & 7;
    const int yb  = blockIdx.x >> 3;       // 0..63, rows 4*yb..4*yb+3
    const int mi_raw = *max_itr;
    const int mi = (mi_raw > 10) ? 10 : mi_raw;

    // ---- TG slice into registers (planar loads; each thread keeps 4 px) ----
    uint4 rT[4], rGX[4], rGY[4];
    {
        const size_t base = (size_t)b * HW + (size_t)yb * 1024 + tid;
        #pragma unroll
        for (int sub = 0; sub < 4; ++sub) {
            const size_t px = base + (size_t)(sub * 256);
            rT[sub] = TGt[px]; rGX[sub] = TGx[px]; rGY[sub] = TGy[px];
        }
    }

    for (int it = 0; it < mi; ++it) {
        if (it > 0) {
            // ---- wait: 64 parallel flag polls (wave 0), no RMW chain ----
            if (tid < 64) wait_flags64(&iterFlags[(size_t)(b * 640 + (it - 1) * 64) * 16], tid);
            if (it == 1 && tid == 0) wait_count(&invHflag[b * 16], 1u);
            __syncthreads();
            if (it == 1 && tid < 64) sh_invH[tid] = cloadd(&invHg[b * 64 + tid]);
            // ---- state reconstruction (coherent reads; identical FP/block) ----
            {
                const float* sR = ((it & 1) ? sP0 : sP1) + b * 512;
                const int e = tid >> 5, l = tid & 31;
                float v = cloadf(&sR[e * 64 + l]) + cloadf(&sR[e * 64 + 32 + l]);
                v = half_reduce(v);
                if (l == 0) s8[e] = v;
            }
            __syncthreads();
            if (tid < 8) {
                double nrm2 = 0.0;
                #pragma unroll
                for (int k2 = 0; k2 < 8; ++k2) {
                    const double d = sh_pd[8 + k2];
                    nrm2 += d * d;
                }
                double dpn = 0.0;
                if (tid < 6) {
                    #pragma unroll
                    for (int k2 = 0; k2 < 8; ++k2)
                        dpn += sh_invH[tid * 8 + k2] * (double)s8[k2];
                }
                const double dp2 = (sqrt(nrm2) > 1e-3) ? dpn : 0.0;
                const double pnew = sh_pd[tid] - dp2;
                sh_pd[tid]     = pnew;
                sh_pd[8 + tid] = dp2;
            }
            __syncthreads();
        } else {
            if (tid < 8) {
                sh_pd[tid]     = (double)init_param[b * 8 + tid];
                sh_pd[8 + tid] = 1.0;
            }
            __syncthreads();
        }

        const float h00 = 1.f + (float)sh_pd[0], h01 = (float)sh_pd[1], h02 = (float)sh_pd[2];
        const float h10 = (float)sh_pd[3], h11 = 1.f + (float)sh_pd[4], h12 = (float)sh_pd[5];
        const float h20 = (float)sh_pd[6], h21 = (float)sh_pd[7];

        // ---- pixel phase: 4 px/thread fully unrolled (16 gathers) ----
        float aa[8];
        #pragma unroll
        for (int e = 0; e < 8; ++e) aa[e] = 0.f;
        #pragma unroll
        for (int sub = 0; sub < 4; ++sub) {
            pixel_accum(imgT, rT[sub], rGX[sub], rGY[sub], b, tid, yb * 4 + sub,
                        h00, h01, h02, h10, h11, h12, h20, h21, aa);
        }

        // ---- block reduce -> 8 coherent partial stores per block ----
        #pragma unroll
        for (int e = 0; e < 8; ++e) red[e * 256 + tid] = aa[e];
        __syncthreads();
        {
            const int e = tid >> 5, l = tid & 31;
            float v = 0.f;
            #pragma unroll
            for (int j = 0; j < 8; ++j) v += red[e * 256 + l + 32 * j];
            v = half_reduce(v);
            if (l == 0) {
                float* sW = (it & 1) ? sP1 : sP0;
                cstoref(&sW[b * 512 + e * 64 + yb], v);
            }
        }

        // ---- arrive: drain partials, then one flag store (own line) ----
        asm volatile("s_waitcnt vmcnt(0)" ::: "memory");
        __syncthreads();
        if (tid == 0)
            cstoreu(&iterFlags[(size_t)(b * 640 + it * 64 + yb) * 16], 1u);

        // ---- iter 0, yb==0: Gram reduce + f64 Gauss-Jordan, publish invH ----
        if (it == 0 && yb == 0) {
            if (tid < 144) {
                const int e = tid >> 2, q = tid & 3;
                const double* gp = gramP + ((size_t)b * 36 + e) * 256 + q * 64;
                double acc = 0.0;
                #pragma unroll 8
                for (int i = 0; i < 64; ++i) acc += gp[i];
                gpart[tid] = acc;
            }
            __syncthreads();
            const int i = tid >> 3, j = tid & 7;
            if (tid < 64) {
                const int pp = min(i, j), qq = max(i, j);
                const int tri = 8 * pp - (pp * (pp - 1)) / 2 + (qq - pp);
                shA[tid] = gpart[tri * 4] + gpart[tri * 4 + 1]
                         + gpart[tri * 4 + 2] + gpart[tri * 4 + 3];
                shB[tid] = (i == j) ? 1.0 : 0.0;
            }
            __syncthreads();
            for (int k = 0; k < 8; ++k) {
                const double piv = shA[k * 8 + k];
                __syncthreads();
                if (tid < 64 && i == k) { shA[tid] /= piv; shB[tid] /= piv; }
                __syncthreads();
                double f = 0, ak = 0, bk = 0;
                if (tid < 64) { f = shA[i * 8 + k]; ak = shA[k * 8 + j]; bk = shB[k * 8 + j]; }
                __syncthreads();
                if (tid < 64 && i != k) { shA[tid] -= f * ak; shB[tid] -= f * bk; }
                __syncthreads();
            }
            if (tid < 64) { cstored(&invHg[b * 64 + tid], shB[tid]);
                            sh_invH[tid] = shB[tid]; }   // stash (mi==1 output)
            asm volatile("s_waitcnt vmcnt(0)" ::: "memory");
            __syncthreads();
            if (tid == 0) cstoreu(&invHflag[b * 16], 1u);
        }
    }

    // ========================= OUTPUT phase ================================
    if (yb != 0) return;                  // 8 blocks, one per batch
    if (mi <= 0) {
        if (tid < 8) out[b * 8 + tid] = init_param[b * 8 + tid];
        if (tid < 9) {
            float v = (tid < 8) ? init_param[b * 8 + tid] : 0.f;
            if (tid == 0 || tid == 4 || tid == 8) v += 1.f;
            out[64 + b * 9 + tid] = v;
        }
        return;
    }
    if (tid < 64) wait_flags64(&iterFlags[(size_t)(b * 640 + (mi - 1) * 64) * 16], tid);
    __syncthreads();
    // sh_invH present: stashed at it==0 (covers mi==1) or loaded at it==1.
    {
        const float* sb = (((mi - 1) & 1) ? sP1 : sP0) + b * 512;
        const int e = tid >> 5, l = tid & 31;
        float v = cloadf(&sb[e * 64 + l]) + cloadf(&sb[e * 64 + 32 + l]);
        v = half_reduce(v);
        if (l == 0) s8[e] = v;
    }
    __syncthreads();
    if (tid < 8) {
        double nrm2 = 0.0;
        #pragma unroll
        for (int k2 = 0; k2 < 8; ++k2) {
            const double d = sh_pd[8 + k2];     // dp of last iteration
            nrm2 += d * d;
        }
        double dpn = 0.0;
        if (tid < 6) {
            #pragma unroll
            for (int k2 = 0; k2 < 8; ++k2)
                dpn += sh_invH[tid * 8 + k2] * (double)s8[k2];
        }
        const double dp2 = (sqrt(nrm2) > 1e-3) ? dpn : 0.0;
        const float pf = (float)(sh_pd[tid] - dp2);
        sh_pf[tid] = pf;
        out[b * 8 + tid] = pf;
    }
    __syncthreads();
    if (tid < 9) {
        float v2 = (tid < 8) ? sh_pf[tid] : 0.f;
        if (tid == 0 || tid == 4 || tid == 8) v2 += 1.f;
        out[64 + b * 9 + tid] = v2;
    }
}

extern "C" void kernel_launch(void* const* d_in, const int* in_sizes, int n_in,
                              void* d_out, int out_size, void* d_ws, size_t ws_size,
                              hipStream_t stream) {
    const float* img        = (const float*)d_in[0];
    const float* temp       = (const float*)d_in[1];
    const float* init_param = (const float*)d_in[2];
    const int*   max_itr    = (const int*)d_in[3];
    float* out = (float*)d_out;

    char* w = (char*)d_ws;
    double* gramP = (double*)w;                        // 576 KB
    double* invHg = gramP + 73728;                     // 4 KB
    float*  sP0   = (float*)(invHg + 512);             // 16 KB
    float*  sP1   = sP0 + 4096;                        // 16 KB
    unsigned int* iterFlags = (unsigned int*)(sP1 + 4096);   // 8*640*64B = 320 KB
    unsigned int* invHflag  = iterFlags + 8 * 640 * 16;      // 8 * 64 B
    uint4* imgT   = (uint4*)(w + 1048576);             // 8.39 MB (bf16 x8 / px)
    uint4* TGt    = (uint4*)(w + 1048576 + 8388608);   // planar T / GX / GY
    uint4* TGx    = TGt + (size_t)B_ * HW;
    uint4* TGy    = TGx + (size_t)B_ * HW;

    prep_kernel<<<B_ * H_, 256, 0, stream>>>(img, temp, imgT, TGt, TGx, TGy,
                                             gramP, iterFlags, invHflag);
    // 512 blocks == 256 CU x 2: residency by capacity (LDS ~11 KB; (256,2)
    // caps VGPR at 256 -> 2 blocks/CU always fit). Proven R11 envelope.
    fused_kernel<<<512, 256, 0, stream>>>(imgT, TGt, TGx, TGy, gramP, invHg,
                                          init_param, sP0, sP1,
                                          iterFlags, invHflag, max_itr, out);
}